// Round 22
// baseline (129.423 us; speedup 1.0000x reference)
//
#include <hip/hip_runtime.h>
#include <hip/hip_fp16.h>

#define WS_ALIGN(x) (((x) + size_t(255)) & ~size_t(255))
#define NB1  8
#define NSUB 128            // sub-buckets per bucket
#define NSB  (NB1 * NSUB)   // 1024 total
#define SPG  98             // cols per sub-bucket = ceil(12500/128)
#define CAP1 262144
#define CAP2 3072           // mean 1562 edges/sub, sigma ~40 -> huge margin

typedef _Float16 f16x8 __attribute__((ext_vector_type(8)));
typedef float f32x4 __attribute__((ext_vector_type(4)));

// ---- tiny counter zeroing
__global__ __launch_bounds__(256) void k_zero(int* __restrict__ p, int n) {
    int i = blockIdx.x * 256 + threadIdx.x;
    if (i < n) p[i] = 0;
}

// ---- Phase A: partition edges into 8 col-range buckets. Packed edge:
// row (17b) << 14 | local_col (14b, < 12500). Block-tiled LDS histogram ->
// ONE padded global atomicAdd per bucket per block.
__global__ __launch_bounds__(256) void k_bucket(const int* __restrict__ row,
                                                const int* __restrict__ col,
                                                int* __restrict__ bcur,   // stride 16 ints
                                                unsigned int* __restrict__ pairs,
                                                int E, unsigned int magic, int npg) {
    __shared__ int lcnt[4][8];
    __shared__ int wbase[4][8];
    int wid = threadIdx.x >> 6;
    if (threadIdx.x < 32) lcnt[threadIdx.x >> 3][threadIdx.x & 7] = 0;
    __syncthreads();

    int t0 = blockIdx.x * 2048;
    int b[8], rk[8];
    unsigned int pk[8];
#pragma unroll
    for (int k = 0; k < 8; k++) {
        int e = t0 + k * 256 + threadIdx.x;
        b[k] = -1;
        if (e < E) {
            int r = row[e], c = col[e];
            int bb = (int)(((unsigned long long)(unsigned)c * magic) >> 44);  // c/npg
            b[k] = bb;
            pk[k] = ((unsigned)r << 14) | (unsigned)(c - bb * npg);
            rk[k] = atomicAdd(&lcnt[wid][bb], 1);
        }
    }
    __syncthreads();
    if (threadIdx.x < 8) {
        int bb = threadIdx.x;
        int c0 = lcnt[0][bb], c1 = lcnt[1][bb], c2 = lcnt[2][bb], c3 = lcnt[3][bb];
        int tot = (c0 + c1) + (c2 + c3);
        int base = tot ? atomicAdd(&bcur[bb * 16], tot) : 0;
        wbase[0][bb] = base;
        wbase[1][bb] = base + c0;
        wbase[2][bb] = base + c0 + c1;
        wbase[3][bb] = base + c0 + c1 + c2;
    }
    __syncthreads();
#pragma unroll
    for (int k = 0; k < 8; k++) {
        if (b[k] >= 0)
            pairs[(size_t)b[k] * CAP1 + wbase[wid][b[k]] + rk[k]] = pk[k];
    }
}

// ---- Phase B: refine bucket b into 128 sub-buckets of SPG cols (lc/98 via magic).
__global__ __launch_bounds__(256) void k_refine(const unsigned int* __restrict__ pairs1,
                                                const int* __restrict__ bcur,
                                                int* __restrict__ bcur2,  // stride 16 ints
                                                unsigned int* __restrict__ pairs2,
                                                unsigned int magic2) {
    __shared__ int lcnt[4][NSUB];
    __shared__ int wbase[4][NSUB];
    int b = blockIdx.x & 7;
    int j = blockIdx.x >> 3;
    int nblk = gridDim.x >> 3;
    int wid = threadIdx.x >> 6;
    int cnt = bcur[b * 16];
    const unsigned int* src = pairs1 + (size_t)b * CAP1;
    unsigned int* dst = pairs2 + (size_t)b * NSUB * CAP2;
    int* mycur = bcur2 + b * NSUB * 16;

    for (int t0 = j * 4096; t0 < cnt; t0 += nblk * 4096) {
        for (int q = threadIdx.x; q < NSUB; q += 256) {
            lcnt[0][q] = 0; lcnt[1][q] = 0; lcnt[2][q] = 0; lcnt[3][q] = 0;
        }
        __syncthreads();
        unsigned int pk[16];
        int sb[16], rk[16];
#pragma unroll
        for (int k = 0; k < 16; k++) {
            int e = t0 + k * 256 + threadIdx.x;
            sb[k] = -1;
            if (e < cnt) {
                pk[k] = src[e];
                sb[k] = (int)(((pk[k] & 16383u) * magic2) >> 20);   // lc/SPG
                rk[k] = atomicAdd(&lcnt[wid][sb[k]], 1);
            }
        }
        __syncthreads();
        for (int q = threadIdx.x; q < NSUB; q += 256) {
            int c0 = lcnt[0][q], c1 = lcnt[1][q], c2 = lcnt[2][q], c3 = lcnt[3][q];
            int tot = (c0 + c1) + (c2 + c3);
            int base = tot ? atomicAdd(&mycur[q * 16], tot) : 0;
            wbase[0][q] = base;
            wbase[1][q] = base + c0;
            wbase[2][q] = base + c0 + c1;
            wbase[3][q] = base + c0 + c1 + c2;
        }
        __syncthreads();
#pragma unroll
        for (int k = 0; k < 16; k++) {
            if (sb[k] >= 0)
                dst[(size_t)sb[k] * CAP2 + wbase[wid][sb[k]] + rk[k]] = pk[k];
        }
        __syncthreads();
    }
}

// ---- degree -> dinv directly (needed by gemm1 for pre-scaling).
__global__ __launch_bounds__(256) void k_degdinv(const unsigned int* __restrict__ pairs2,
                                                 const int* __restrict__ bcur2,
                                                 float* __restrict__ dinv, int npg) {
    __shared__ int hist[SPG];
    int sbid = blockIdx.x;
    int b = sbid >> 7, s = sbid & (NSUB - 1);
    int cnt = bcur2[sbid * 16];
    int sbase = s * SPG;
    int ncols = min(SPG, npg - sbase);
    const unsigned int* src = pairs2 + (size_t)sbid * CAP2;
    for (int q = threadIdx.x; q < SPG; q += 256) hist[q] = 0;
    __syncthreads();
    for (int i = threadIdx.x; i < cnt; i += 256)
        atomicAdd(&hist[(int)(src[i] & 16383u) - sbase], 1);
    __syncthreads();
    if (threadIdx.x < ncols)
        dinv[b * npg + sbase + threadIdx.x] = rsqrtf((float)(hist[threadIdx.x] + 1));
}

// h1s = fp16[(x @ W1) * dinv[node]] via MFMA 16x16x32 f16 with coalesced
// LDS staging (r21).
__global__ __launch_bounds__(256) void k_gemm1(const float* __restrict__ x,
                                               const float* __restrict__ W1,
                                               const float* __restrict__ dinv,
                                               __half* __restrict__ h1s, int n) {
    __shared__ _Float16 Wt[64][136];
    __shared__ _Float16 xh[64][136];
    int base = blockIdx.x * 64;
    for (int q = threadIdx.x; q < 2048; q += 256) {
        float4 v = ((const float4*)W1)[q];
        int k = q >> 4, c = (q & 15) * 4;
        Wt[c][k]     = (_Float16)v.x;
        Wt[c + 1][k] = (_Float16)v.y;
        Wt[c + 2][k] = (_Float16)v.z;
        Wt[c + 3][k] = (_Float16)v.w;
    }
    for (int q = threadIdx.x; q < 2048; q += 256) {
        int nd = q >> 5, kf = (q & 31) * 4;
        int gn = base + nd;
        float4 v = (gn < n) ? *(const float4*)&x[(size_t)gn * 128 + kf]
                            : make_float4(0.f, 0.f, 0.f, 0.f);
        xh[nd][kf]     = (_Float16)v.x;
        xh[nd][kf + 1] = (_Float16)v.y;
        xh[nd][kf + 2] = (_Float16)v.z;
        xh[nd][kf + 3] = (_Float16)v.w;
    }
    __syncthreads();

    int wid = threadIdx.x >> 6;      // wave -> 16-node tile
    int lane = threadIdx.x & 63;
    int lrow = lane & 15;            // A-row / B-col / D-col
    int kgrp = (lane >> 4) * 8;      // k base for A/B frags
    int r0   = (lane >> 4) * 4;      // D-row base

    f16x8 bfr[4][4];
#pragma unroll
    for (int t = 0; t < 4; t++)
#pragma unroll
        for (int s = 0; s < 4; s++)
            bfr[t][s] = *(const f16x8*)&Wt[t * 16 + lrow][s * 32 + kgrp];

    int node0 = base + wid * 16;
    f32x4 acc[4] = {{0.f, 0.f, 0.f, 0.f}, {0.f, 0.f, 0.f, 0.f},
                    {0.f, 0.f, 0.f, 0.f}, {0.f, 0.f, 0.f, 0.f}};
#pragma unroll
    for (int s = 0; s < 4; s++) {
        f16x8 af = *(const f16x8*)&xh[wid * 16 + lrow][s * 32 + kgrp];
#pragma unroll
        for (int t = 0; t < 4; t++)
            acc[t] = __builtin_amdgcn_mfma_f32_16x16x32_f16(af, bfr[t][s], acc[t], 0, 0, 0);
    }
    int dbase = min(node0 + r0, n - 4);
    float4 dv = *(const float4*)&dinv[max(dbase, 0)];
#pragma unroll
    for (int t = 0; t < 4; t++) {
#pragma unroll
        for (int r = 0; r < 4; r++) {
            int node = node0 + r0 + r;
            if (node < n)
                h1s[(size_t)node * 64 + t * 16 + lrow] =
                    (__half)(acc[t][r] * (&dv.x)[r]);
        }
    }
}

// ---- Fused: LDS counting-sort, then TWO-NODE interleaved 16-lane-group
// gather: each wave processes node pair (2wid, 2wid+1); per while-iteration
// it issues self-masked 4-edge bursts for BOTH nodes (8 VMEM in flight,
// node B's gathers overlap node A's reduce). Loop bounds wave-uniform ->
// no divergent branches; masking via cndmask only.
__global__ __launch_bounds__(512) void k_agg1s(const __half* __restrict__ h1s,
                                               const float* __restrict__ dinv,
                                               const unsigned int* __restrict__ pairs2,
                                               const int* __restrict__ bcur2,
                                               const float* __restrict__ b1,
                                               const float* __restrict__ W2,
                                               float* __restrict__ h2s, int npg) {
    __shared__ int hist[SPG + 2];
    __shared__ int offsL[SPG + 2];
    __shared__ int curL[SPG + 2];
    __shared__ int adjL[CAP2];          // 12 KB
    int sbid = blockIdx.x;
    int b = sbid >> 7, s = sbid & (NSUB - 1);
    int cnt = bcur2[sbid * 16];
    int sbase = s * SPG;
    int colbase = b * npg + sbase;
    int ncols = min(SPG, npg - sbase);
    const unsigned int* src = pairs2 + (size_t)sbid * CAP2;

    for (int q = threadIdx.x; q < SPG + 2; q += 512) hist[q] = 0;
    __syncthreads();
    for (int i = threadIdx.x; i < cnt; i += 512)
        atomicAdd(&hist[(int)(src[i] & 16383u) - sbase], 1);
    __syncthreads();
    // wave 0: exclusive scan of hist[0..SPG) -> offsL
    if (threadIdx.x < 64) {
        int lane = threadIdx.x;
        int v0 = hist[lane];
        int sc0 = v0;
#pragma unroll
        for (int m = 1; m < 64; m <<= 1) {
            int t = __shfl_up(sc0, m, 64);
            if (lane >= m) sc0 += t;
        }
        offsL[lane] = sc0 - v0;
        int tot0 = __shfl(sc0, 63, 64);
        int v1 = (lane < SPG - 64) ? hist[64 + lane] : 0;
        int sc1 = v1;
#pragma unroll
        for (int m = 1; m < 64; m <<= 1) {
            int t = __shfl_up(sc1, m, 64);
            if (lane >= m) sc1 += t;
        }
        if (lane < SPG - 64 + 1) offsL[64 + lane] = tot0 + sc1 - v1;  // includes offsL[SPG]
        if (lane == 0) offsL[SPG] = cnt;
    }
    __syncthreads();
    for (int q = threadIdx.x; q < SPG + 1; q += 512) curL[q] = offsL[q];
    __syncthreads();
    // scatter: store PRE-SCALED element offset sn*64 (throughput ops only)
    for (int i = threadIdx.x; i < cnt; i += 512) {
        unsigned int pk = src[i];
        int lc = (int)(pk & 16383u) - sbase;
        int pos = atomicAdd(&curL[lc], 1);
        adjL[pos] = (int)(pk >> 14) << 6;
    }
    __syncthreads();

    // gather phase: wave per NODE PAIR, stride 16
    int wid = threadIdx.x >> 6, lane = threadIdx.x & 63;
    int sl4 = lane & 15, grp4 = lane >> 4;
    float4 wA = *(const float4*)&W2[8 * sl4];       // ch 4sl4+0,+1 x {0,1}
    float4 wB = *(const float4*)&W2[8 * sl4 + 4];   // ch 4sl4+2,+3 x {0,1}
    float4 bb4 = *(const float4*)&b1[4 * sl4];
    for (int base2 = wid * 2; base2 < ncols; base2 += 16) {
        int ndA = base2, ndB = base2 + 1;
        bool hasB = ndB < ncols;
        int stA = offsL[ndA], enA = offsL[ndA + 1];
        int stB = hasB ? offsL[ndB] : 0;
        int enB = hasB ? offsL[ndB + 1] : 0;
        float a0 = 0.f, a1 = 0.f, a2 = 0.f, a3 = 0.f;
        float c0 = 0.f, c1 = 0.f, c2 = 0.f, c3 = 0.f;
        int pA = stA, pB = stB;
        while (pA < enA || pB < enB) {
            // node A burst (self-masked)
            {
                int idx = pA + grp4;
                bool act = idx < enA;
                int off = adjL[act ? idx : 0];
                float2 raw = *(const float2*)(h1s + off + 4 * sl4);
                float2 f0 = __half22float2(*(const __half2*)&raw.x);
                float2 f1 = __half22float2(*(const __half2*)&raw.y);
                a0 += act ? f0.x : 0.f; a1 += act ? f0.y : 0.f;
                a2 += act ? f1.x : 0.f; a3 += act ? f1.y : 0.f;
            }
            // node B burst (self-masked)
            {
                int idx = pB + grp4;
                bool act = idx < enB;
                int off = adjL[act ? idx : 0];
                float2 raw = *(const float2*)(h1s + off + 4 * sl4);
                float2 f0 = __half22float2(*(const __half2*)&raw.x);
                float2 f1 = __half22float2(*(const __half2*)&raw.y);
                c0 += act ? f0.x : 0.f; c1 += act ? f0.y : 0.f;
                c2 += act ? f1.x : 0.f; c3 += act ? f1.y : 0.f;
            }
            pA += 4; pB += 4;
        }
        // epilogue A
        {
            a0 += __shfl_xor(a0, 16, 64); a0 += __shfl_xor(a0, 32, 64);
            a1 += __shfl_xor(a1, 16, 64); a1 += __shfl_xor(a1, 32, 64);
            a2 += __shfl_xor(a2, 16, 64); a2 += __shfl_xor(a2, 32, 64);
            a3 += __shfl_xor(a3, 16, 64); a3 += __shfl_xor(a3, 32, 64);
            int i = colbase + ndA;
            float di = dinv[i];
            float2 sraw = *(const float2*)(h1s + ((size_t)i << 6) + 4 * sl4);
            float2 s0 = __half22float2(*(const __half2*)&sraw.x);
            float2 s1 = __half22float2(*(const __half2*)&sraw.y);
            float v0 = fmaxf(fmaf(di, a0 + s0.x, bb4.x), 0.f);
            float v1 = fmaxf(fmaf(di, a1 + s0.y, bb4.y), 0.f);
            float v2 = fmaxf(fmaf(di, a2 + s1.x, bb4.z), 0.f);
            float v3 = fmaxf(fmaf(di, a3 + s1.y, bb4.w), 0.f);
            float t0 = fmaf(v1, wA.z, v0 * wA.x);
            t0 = fmaf(v2, wB.x, t0); t0 = fmaf(v3, wB.z, t0);
            float t1 = fmaf(v1, wA.w, v0 * wA.y);
            t1 = fmaf(v2, wB.y, t1); t1 = fmaf(v3, wB.w, t1);
#pragma unroll
            for (int m2 = 1; m2 < 16; m2 <<= 1) {
                t0 += __shfl_xor(t0, m2, 64);
                t1 += __shfl_xor(t1, m2, 64);
            }
            if (lane == 0) {
                h2s[(size_t)i * 2]     = t0 * di;
                h2s[(size_t)i * 2 + 1] = t1 * di;
            }
        }
        // epilogue B
        if (hasB) {
            c0 += __shfl_xor(c0, 16, 64); c0 += __shfl_xor(c0, 32, 64);
            c1 += __shfl_xor(c1, 16, 64); c1 += __shfl_xor(c1, 32, 64);
            c2 += __shfl_xor(c2, 16, 64); c2 += __shfl_xor(c2, 32, 64);
            c3 += __shfl_xor(c3, 16, 64); c3 += __shfl_xor(c3, 32, 64);
            int i = colbase + ndB;
            float di = dinv[i];
            float2 sraw = *(const float2*)(h1s + ((size_t)i << 6) + 4 * sl4);
            float2 s0 = __half22float2(*(const __half2*)&sraw.x);
            float2 s1 = __half22float2(*(const __half2*)&sraw.y);
            float v0 = fmaxf(fmaf(di, c0 + s0.x, bb4.x), 0.f);
            float v1 = fmaxf(fmaf(di, c1 + s0.y, bb4.y), 0.f);
            float v2 = fmaxf(fmaf(di, c2 + s1.x, bb4.z), 0.f);
            float v3 = fmaxf(fmaf(di, c3 + s1.y, bb4.w), 0.f);
            float t0 = fmaf(v1, wA.z, v0 * wA.x);
            t0 = fmaf(v2, wB.x, t0); t0 = fmaf(v3, wB.z, t0);
            float t1 = fmaf(v1, wA.w, v0 * wA.y);
            t1 = fmaf(v2, wB.y, t1); t1 = fmaf(v3, wB.w, t1);
#pragma unroll
            for (int m2 = 1; m2 < 16; m2 <<= 1) {
                t0 += __shfl_xor(t0, m2, 64);
                t1 += __shfl_xor(t1, m2, 64);
            }
            if (lane == 0) {
                h2s[(size_t)i * 2]     = t0 * di;
                h2s[(size_t)i * 2 + 1] = t1 * di;
            }
        }
    }
}

// ---- Layer-2 aggregation from sub-buckets. Lane-per-edge, 8B gathers from
// L2-resident h2s, 2 LDS float atomics per edge.
__global__ __launch_bounds__(256) void k_agg2f(const float* __restrict__ h2s,
                                               const float* __restrict__ dinv,
                                               const unsigned int* __restrict__ pairs2,
                                               const int* __restrict__ bcur2,
                                               const float* __restrict__ b2,
                                               float* __restrict__ out, int npg) {
    __shared__ float acc2[SPG * 2];
    int sbid = blockIdx.x;
    int b = sbid >> 7, s = sbid & (NSUB - 1);
    int cnt = bcur2[sbid * 16];
    int sbase = s * SPG;
    int colbase = b * npg + sbase;
    int ncols = min(SPG, npg - sbase);
    const unsigned int* src = pairs2 + (size_t)sbid * CAP2;
    for (int q = threadIdx.x; q < SPG * 2; q += 256) acc2[q] = 0.f;
    __syncthreads();
    for (int i = threadIdx.x; i < cnt; i += 256) {
        unsigned int pk = src[i];
        int sn = (int)(pk >> 14);
        int lc = (int)(pk & 16383u) - sbase;
        float2 v = *(const float2*)(h2s + (size_t)sn * 2);
        atomicAdd(&acc2[lc * 2], v.x);
        atomicAdd(&acc2[lc * 2 + 1], v.y);
    }
    __syncthreads();
    if (threadIdx.x < ncols) {
        int i = colbase + threadIdx.x;
        float di = dinv[i];
        float2 hv = *(const float2*)(h2s + (size_t)i * 2);
        out[(size_t)i * 2]     = fmaf(di, acc2[threadIdx.x * 2] + hv.x, b2[0]);
        out[(size_t)i * 2 + 1] = fmaf(di, acc2[threadIdx.x * 2 + 1] + hv.y, b2[1]);
    }
}

extern "C" void kernel_launch(void* const* d_in, const int* in_sizes, int n_in,
                              void* d_out, int out_size, void* d_ws, size_t ws_size,
                              hipStream_t stream) {
    const float* x  = (const float*)d_in[0];
    const int*   ei = (const int*)d_in[1];
    const float* W1 = (const float*)d_in[2];
    const float* b1 = (const float*)d_in[3];
    const float* W2 = (const float*)d_in[4];
    const float* b2 = (const float*)d_in[5];
    float* out = (float*)d_out;

    int N = in_sizes[0] / 128;   // 100000
    int E = in_sizes[1] / 2;     // 1600000
    const int* row = ei;
    const int* col = ei + E;

    char* ws = (char*)d_ws;
    size_t off = 0;
    auto alloc = [&](size_t bytes) -> char* {
        char* p = ws + off;
        off = WS_ALIGN(off + bytes);
        return p;
    };
    int*   bcur   = (int*)alloc(512 + (size_t)NSB * 64);   // bcur (8x16) + bcur2 (1024x16)
    int*   bcur2  = bcur + 128;
    float* dinv   = (float*)alloc((size_t)N * 4);
    unsigned int* pairs1 = (unsigned int*)alloc((size_t)NB1 * CAP1 * 4);   // 8.4MB
    unsigned int* pairs2 = (unsigned int*)alloc((size_t)NSB * CAP2 * 4);   // 12.6MB
    __half* h1s   = (__half*)alloc((size_t)N * 64 * 2);    // 12.8MB fp16
    float* h2s    = (float*)alloc((size_t)N * 2 * 4);

    int npg = (N + 7) / 8;                                  // 12500
    unsigned int magic = (unsigned int)(((1ULL << 44) + (unsigned long long)npg - 1)
                                        / (unsigned long long)npg);
    unsigned int magic2 = (unsigned int)(((1u << 20) + SPG - 1) / SPG);  // /98, exact for lc<12544

    int nzero = 128 + NSB * 16;                             // bcur + bcur2 ints

    hipLaunchKernelGGL(k_zero, dim3((nzero + 255) / 256), dim3(256), 0, stream, bcur, nzero);
    hipLaunchKernelGGL(k_bucket, dim3((E + 2047) / 2048), dim3(256), 0, stream,
                       row, col, bcur, pairs1, E, magic, npg);
    hipLaunchKernelGGL(k_refine, dim3(512), dim3(256), 0, stream,
                       pairs1, bcur, bcur2, pairs2, magic2);
    hipLaunchKernelGGL(k_degdinv, dim3(NSB), dim3(256), 0, stream, pairs2, bcur2, dinv, npg);
    hipLaunchKernelGGL(k_gemm1, dim3((N + 63) / 64), dim3(256), 0, stream, x, W1, dinv, h1s, N);
    hipLaunchKernelGGL(k_agg1s, dim3(NSB), dim3(512), 0, stream,
                       h1s, dinv, pairs2, bcur2, b1, W2, h2s, npg);
    hipLaunchKernelGGL(k_agg2f, dim3(NSB), dim3(256), 0, stream,
                       h2s, dinv, pairs2, bcur2, b2, out, npg);
}

// Round 24
// 125.097 us; speedup vs baseline: 1.0346x; 1.0346x over previous
//
#include <hip/hip_runtime.h>
#include <hip/hip_fp16.h>

#define WS_ALIGN(x) (((x) + size_t(255)) & ~size_t(255))
#define NB1  8
#define NSUB 128            // sub-buckets per bucket
#define NSB  (NB1 * NSUB)   // 1024 total
#define SPG  98             // cols per sub-bucket = ceil(12500/128)
#define CAP1 262144
#define CAP2 3072           // mean 1562 edges/sub, sigma ~40 -> huge margin

typedef _Float16 f16x8 __attribute__((ext_vector_type(8)));
typedef float f32x4 __attribute__((ext_vector_type(4)));

// ---- tiny counter zeroing
__global__ __launch_bounds__(256) void k_zero(int* __restrict__ p, int n) {
    int i = blockIdx.x * 256 + threadIdx.x;
    if (i < n) p[i] = 0;
}

// ---- Phase A: partition edges into 8 col-range buckets. Packed edge:
// row (17b) << 14 | local_col (14b, < 12500). Block-tiled LDS histogram ->
// ONE padded global atomicAdd per bucket per block.
__global__ __launch_bounds__(256) void k_bucket(const int* __restrict__ row,
                                                const int* __restrict__ col,
                                                int* __restrict__ bcur,   // stride 16 ints
                                                unsigned int* __restrict__ pairs,
                                                int E, unsigned int magic, int npg) {
    __shared__ int lcnt[4][8];
    __shared__ int wbase[4][8];
    int wid = threadIdx.x >> 6;
    if (threadIdx.x < 32) lcnt[threadIdx.x >> 3][threadIdx.x & 7] = 0;
    __syncthreads();

    int t0 = blockIdx.x * 2048;
    int b[8], rk[8];
    unsigned int pk[8];
#pragma unroll
    for (int k = 0; k < 8; k++) {
        int e = t0 + k * 256 + threadIdx.x;
        b[k] = -1;
        if (e < E) {
            int r = row[e], c = col[e];
            int bb = (int)(((unsigned long long)(unsigned)c * magic) >> 44);  // c/npg
            b[k] = bb;
            pk[k] = ((unsigned)r << 14) | (unsigned)(c - bb * npg);
            rk[k] = atomicAdd(&lcnt[wid][bb], 1);
        }
    }
    __syncthreads();
    if (threadIdx.x < 8) {
        int bb = threadIdx.x;
        int c0 = lcnt[0][bb], c1 = lcnt[1][bb], c2 = lcnt[2][bb], c3 = lcnt[3][bb];
        int tot = (c0 + c1) + (c2 + c3);
        int base = tot ? atomicAdd(&bcur[bb * 16], tot) : 0;
        wbase[0][bb] = base;
        wbase[1][bb] = base + c0;
        wbase[2][bb] = base + c0 + c1;
        wbase[3][bb] = base + c0 + c1 + c2;
    }
    __syncthreads();
#pragma unroll
    for (int k = 0; k < 8; k++) {
        if (b[k] >= 0)
            pairs[(size_t)b[k] * CAP1 + wbase[wid][b[k]] + rk[k]] = pk[k];
    }
}

// ---- Phase B: refine bucket b into 128 sub-buckets of SPG cols (lc/98 via magic).
__global__ __launch_bounds__(256) void k_refine(const unsigned int* __restrict__ pairs1,
                                                const int* __restrict__ bcur,
                                                int* __restrict__ bcur2,  // stride 16 ints
                                                unsigned int* __restrict__ pairs2,
                                                unsigned int magic2) {
    __shared__ int lcnt[4][NSUB];
    __shared__ int wbase[4][NSUB];
    int b = blockIdx.x & 7;
    int j = blockIdx.x >> 3;
    int nblk = gridDim.x >> 3;
    int wid = threadIdx.x >> 6;
    int cnt = bcur[b * 16];
    const unsigned int* src = pairs1 + (size_t)b * CAP1;
    unsigned int* dst = pairs2 + (size_t)b * NSUB * CAP2;
    int* mycur = bcur2 + b * NSUB * 16;

    for (int t0 = j * 4096; t0 < cnt; t0 += nblk * 4096) {
        for (int q = threadIdx.x; q < NSUB; q += 256) {
            lcnt[0][q] = 0; lcnt[1][q] = 0; lcnt[2][q] = 0; lcnt[3][q] = 0;
        }
        __syncthreads();
        unsigned int pk[16];
        int sb[16], rk[16];
#pragma unroll
        for (int k = 0; k < 16; k++) {
            int e = t0 + k * 256 + threadIdx.x;
            sb[k] = -1;
            if (e < cnt) {
                pk[k] = src[e];
                sb[k] = (int)(((pk[k] & 16383u) * magic2) >> 20);   // lc/SPG
                rk[k] = atomicAdd(&lcnt[wid][sb[k]], 1);
            }
        }
        __syncthreads();
        for (int q = threadIdx.x; q < NSUB; q += 256) {
            int c0 = lcnt[0][q], c1 = lcnt[1][q], c2 = lcnt[2][q], c3 = lcnt[3][q];
            int tot = (c0 + c1) + (c2 + c3);
            int base = tot ? atomicAdd(&mycur[q * 16], tot) : 0;
            wbase[0][q] = base;
            wbase[1][q] = base + c0;
            wbase[2][q] = base + c0 + c1;
            wbase[3][q] = base + c0 + c1 + c2;
        }
        __syncthreads();
#pragma unroll
        for (int k = 0; k < 16; k++) {
            if (sb[k] >= 0)
                dst[(size_t)sb[k] * CAP2 + wbase[wid][sb[k]] + rk[k]] = pk[k];
        }
        __syncthreads();
    }
}

// ---- degree -> dinv directly (needed by gemm1 for pre-scaling).
__global__ __launch_bounds__(256) void k_degdinv(const unsigned int* __restrict__ pairs2,
                                                 const int* __restrict__ bcur2,
                                                 float* __restrict__ dinv, int npg) {
    __shared__ int hist[SPG];
    int sbid = blockIdx.x;
    int b = sbid >> 7, s = sbid & (NSUB - 1);
    int cnt = bcur2[sbid * 16];
    int sbase = s * SPG;
    int ncols = min(SPG, npg - sbase);
    const unsigned int* src = pairs2 + (size_t)sbid * CAP2;
    for (int q = threadIdx.x; q < SPG; q += 256) hist[q] = 0;
    __syncthreads();
    for (int i = threadIdx.x; i < cnt; i += 256)
        atomicAdd(&hist[(int)(src[i] & 16383u) - sbase], 1);
    __syncthreads();
    if (threadIdx.x < ncols)
        dinv[b * npg + sbase + threadIdx.x] = rsqrtf((float)(hist[threadIdx.x] + 1));
}

// h1s = fp16[(x @ W1) * dinv[node]] via MFMA 16x16x32 f16 (r17, measured).
__global__ __launch_bounds__(256) void k_gemm1(const float* __restrict__ x,
                                               const float* __restrict__ W1,
                                               const float* __restrict__ dinv,
                                               __half* __restrict__ h1s, int n) {
    __shared__ _Float16 Wt[64][136];
    for (int q = threadIdx.x; q < 2048; q += 256) {
        float4 v = ((const float4*)W1)[q];
        int k = q >> 4, c = (q & 15) * 4;
        Wt[c][k]     = (_Float16)v.x;
        Wt[c + 1][k] = (_Float16)v.y;
        Wt[c + 2][k] = (_Float16)v.z;
        Wt[c + 3][k] = (_Float16)v.w;
    }
    __syncthreads();

    int lane = threadIdx.x & 63;
    int lrow = lane & 15;            // A-row / B-col / D-col
    int kgrp = (lane >> 4) * 8;      // k base for A/B frags
    int r0   = (lane >> 4) * 4;      // D-row base
    int wglobal = (blockIdx.x * 256 + threadIdx.x) >> 6;
    int nwaves  = (gridDim.x * 256) >> 6;
    int ntiles  = (n + 15) >> 4;

    f16x8 bfr[4][4];
#pragma unroll
    for (int t = 0; t < 4; t++)
#pragma unroll
        for (int s = 0; s < 4; s++)
            bfr[t][s] = *(const f16x8*)&Wt[t * 16 + lrow][s * 32 + kgrp];

    for (int tile = wglobal; tile < ntiles; tile += nwaves) {
        int node0 = tile << 4;
        int arow = min(node0 + lrow, n - 1);
        const float* xr = x + (size_t)arow * 128;
        f32x4 acc[4] = {{0.f, 0.f, 0.f, 0.f}, {0.f, 0.f, 0.f, 0.f},
                        {0.f, 0.f, 0.f, 0.f}, {0.f, 0.f, 0.f, 0.f}};
#pragma unroll
        for (int s = 0; s < 4; s++) {
            float4 u0 = *(const float4*)&xr[s * 32 + kgrp];
            float4 u1 = *(const float4*)&xr[s * 32 + kgrp + 4];
            f16x8 af;
            af[0] = (_Float16)u0.x; af[1] = (_Float16)u0.y;
            af[2] = (_Float16)u0.z; af[3] = (_Float16)u0.w;
            af[4] = (_Float16)u1.x; af[5] = (_Float16)u1.y;
            af[6] = (_Float16)u1.z; af[7] = (_Float16)u1.w;
#pragma unroll
            for (int t = 0; t < 4; t++)
                acc[t] = __builtin_amdgcn_mfma_f32_16x16x32_f16(af, bfr[t][s], acc[t], 0, 0, 0);
        }
        int dbase = min(node0 + r0, n - 4);
        float4 dv = *(const float4*)&dinv[dbase];
#pragma unroll
        for (int t = 0; t < 4; t++) {
#pragma unroll
            for (int r = 0; r < 4; r++) {
                int node = node0 + r0 + r;
                if (node < n)
                    h1s[(size_t)node * 64 + t * 16 + lrow] =
                        (__half)(acc[t][r] * (&dv.x)[r]);
            }
        }
    }
}

// ---- Fused: LDS counting-sort, then 16-LANE-GROUP gather: four 16-lane
// groups each gather a DIFFERENT edge; each lane loads 8B (dwordx2 = 4 fp16
// channels). Per 4 edges: 1 LDS adjL read + 1 VMEM + ~8 VALU.
__global__ __launch_bounds__(512) void k_agg1s(const __half* __restrict__ h1s,
                                               const float* __restrict__ dinv,
                                               const unsigned int* __restrict__ pairs2,
                                               const int* __restrict__ bcur2,
                                               const float* __restrict__ b1,
                                               const float* __restrict__ W2,
                                               float* __restrict__ h2s, int npg) {
    __shared__ int hist[SPG + 2];
    __shared__ int offsL[SPG + 2];
    __shared__ int curL[SPG + 2];
    __shared__ int adjL[CAP2];          // 12 KB
    int sbid = blockIdx.x;
    int b = sbid >> 7, s = sbid & (NSUB - 1);
    int cnt = bcur2[sbid * 16];
    int sbase = s * SPG;
    int colbase = b * npg + sbase;
    int ncols = min(SPG, npg - sbase);
    const unsigned int* src = pairs2 + (size_t)sbid * CAP2;

    for (int q = threadIdx.x; q < SPG + 2; q += 512) hist[q] = 0;
    __syncthreads();
    for (int i = threadIdx.x; i < cnt; i += 512)
        atomicAdd(&hist[(int)(src[i] & 16383u) - sbase], 1);
    __syncthreads();
    // wave 0: exclusive scan of hist[0..SPG) -> offsL
    if (threadIdx.x < 64) {
        int lane = threadIdx.x;
        int v0 = hist[lane];
        int sc0 = v0;
#pragma unroll
        for (int m = 1; m < 64; m <<= 1) {
            int t = __shfl_up(sc0, m, 64);
            if (lane >= m) sc0 += t;
        }
        offsL[lane] = sc0 - v0;
        int tot0 = __shfl(sc0, 63, 64);
        int v1 = (lane < SPG - 64) ? hist[64 + lane] : 0;
        int sc1 = v1;
#pragma unroll
        for (int m = 1; m < 64; m <<= 1) {
            int t = __shfl_up(sc1, m, 64);
            if (lane >= m) sc1 += t;
        }
        if (lane < SPG - 64 + 1) offsL[64 + lane] = tot0 + sc1 - v1;  // includes offsL[SPG]
        if (lane == 0) offsL[SPG] = cnt;
    }
    __syncthreads();
    for (int q = threadIdx.x; q < SPG + 1; q += 512) curL[q] = offsL[q];
    __syncthreads();
    // scatter: store PRE-SCALED element offset sn*64 (throughput ops only)
    for (int i = threadIdx.x; i < cnt; i += 512) {
        unsigned int pk = src[i];
        int lc = (int)(pk & 16383u) - sbase;
        int pos = atomicAdd(&curL[lc], 1);
        adjL[pos] = (int)(pk >> 14) << 6;
    }
    __syncthreads();

    // gather phase: wave per node, stride 8; 16-lane-group dwordx2 gathers
    int wid = threadIdx.x >> 6, lane = threadIdx.x & 63;
    int sl4 = lane & 15, grp4 = lane >> 4;
    float4 wA = *(const float4*)&W2[8 * sl4];       // ch 4sl4+0,+1 x {0,1}
    float4 wB = *(const float4*)&W2[8 * sl4 + 4];   // ch 4sl4+2,+3 x {0,1}
    float4 bb4 = *(const float4*)&b1[4 * sl4];
    for (int nd = wid; nd < ncols; nd += 8) {
        int st = offsL[nd], en = offsL[nd + 1];
        float a0 = 0.f, a1 = 0.f, a2 = 0.f, a3 = 0.f;
        int p = st;
        for (; p + 16 <= en; p += 16) {
#pragma unroll
            for (int j = 0; j < 4; j++) {
                int off = adjL[p + 4 * j + grp4];
                float2 raw = *(const float2*)(h1s + off + 4 * sl4);
                float2 f0 = __half22float2(*(const __half2*)&raw.x);
                float2 f1 = __half22float2(*(const __half2*)&raw.y);
                a0 += f0.x; a1 += f0.y; a2 += f1.x; a3 += f1.y;
            }
        }
        for (; p + 4 <= en; p += 4) {
            int off = adjL[p + grp4];
            float2 raw = *(const float2*)(h1s + off + 4 * sl4);
            float2 f0 = __half22float2(*(const __half2*)&raw.x);
            float2 f1 = __half22float2(*(const __half2*)&raw.y);
            a0 += f0.x; a1 += f0.y; a2 += f1.x; a3 += f1.y;
        }
        if (p < en) {                                  // masked tail (<4)
            int idx = p + grp4;
            int off = adjL[(idx < en) ? idx : p];
            float2 raw = *(const float2*)(h1s + off + 4 * sl4);
            float2 f0 = __half22float2(*(const __half2*)&raw.x);
            float2 f1 = __half22float2(*(const __half2*)&raw.y);
            bool act = idx < en;
            a0 += act ? f0.x : 0.f; a1 += act ? f0.y : 0.f;
            a2 += act ? f1.x : 0.f; a3 += act ? f1.y : 0.f;
        }
        // combine the four edge-subsets
        a0 += __shfl_xor(a0, 16, 64); a0 += __shfl_xor(a0, 32, 64);
        a1 += __shfl_xor(a1, 16, 64); a1 += __shfl_xor(a1, 32, 64);
        a2 += __shfl_xor(a2, 16, 64); a2 += __shfl_xor(a2, 32, 64);
        a3 += __shfl_xor(a3, 16, 64); a3 += __shfl_xor(a3, 32, 64);
        int i = colbase + nd;
        float di = dinv[i];
        float2 sraw = *(const float2*)(h1s + ((size_t)i << 6) + 4 * sl4);
        float2 s0 = __half22float2(*(const __half2*)&sraw.x);
        float2 s1 = __half22float2(*(const __half2*)&sraw.y);
        float v0 = fmaxf(fmaf(di, a0 + s0.x, bb4.x), 0.f);
        float v1 = fmaxf(fmaf(di, a1 + s0.y, bb4.y), 0.f);
        float v2 = fmaxf(fmaf(di, a2 + s1.x, bb4.z), 0.f);
        float v3 = fmaxf(fmaf(di, a3 + s1.y, bb4.w), 0.f);
        float t0 = fmaf(v1, wA.z, v0 * wA.x);
        t0 = fmaf(v2, wB.x, t0); t0 = fmaf(v3, wB.z, t0);
        float t1 = fmaf(v1, wA.w, v0 * wA.y);
        t1 = fmaf(v2, wB.y, t1); t1 = fmaf(v3, wB.w, t1);
#pragma unroll
        for (int m2 = 1; m2 < 16; m2 <<= 1) {
            t0 += __shfl_xor(t0, m2, 64);
            t1 += __shfl_xor(t1, m2, 64);
        }
        if (lane == 0) {
            h2s[(size_t)i * 2]     = t0 * di;
            h2s[(size_t)i * 2 + 1] = t1 * di;
        }
    }
}

// ---- Layer-2 aggregation from sub-buckets. Lane-per-edge, 8B gathers from
// L2-resident h2s, 2 LDS float atomics per edge.
__global__ __launch_bounds__(256) void k_agg2f(const float* __restrict__ h2s,
                                               const float* __restrict__ dinv,
                                               const unsigned int* __restrict__ pairs2,
                                               const int* __restrict__ bcur2,
                                               const float* __restrict__ b2,
                                               float* __restrict__ out, int npg) {
    __shared__ float acc2[SPG * 2];
    int sbid = blockIdx.x;
    int b = sbid >> 7, s = sbid & (NSUB - 1);
    int cnt = bcur2[sbid * 16];
    int sbase = s * SPG;
    int colbase = b * npg + sbase;
    int ncols = min(SPG, npg - sbase);
    const unsigned int* src = pairs2 + (size_t)sbid * CAP2;
    for (int q = threadIdx.x; q < SPG * 2; q += 256) acc2[q] = 0.f;
    __syncthreads();
    for (int i = threadIdx.x; i < cnt; i += 256) {
        unsigned int pk = src[i];
        int sn = (int)(pk >> 14);
        int lc = (int)(pk & 16383u) - sbase;
        float2 v = *(const float2*)(h2s + (size_t)sn * 2);
        atomicAdd(&acc2[lc * 2], v.x);
        atomicAdd(&acc2[lc * 2 + 1], v.y);
    }
    __syncthreads();
    if (threadIdx.x < ncols) {
        int i = colbase + threadIdx.x;
        float di = dinv[i];
        float2 hv = *(const float2*)(h2s + (size_t)i * 2);
        out[(size_t)i * 2]     = fmaf(di, acc2[threadIdx.x * 2] + hv.x, b2[0]);
        out[(size_t)i * 2 + 1] = fmaf(di, acc2[threadIdx.x * 2 + 1] + hv.y, b2[1]);
    }
}

extern "C" void kernel_launch(void* const* d_in, const int* in_sizes, int n_in,
                              void* d_out, int out_size, void* d_ws, size_t ws_size,
                              hipStream_t stream) {
    const float* x  = (const float*)d_in[0];
    const int*   ei = (const int*)d_in[1];
    const float* W1 = (const float*)d_in[2];
    const float* b1 = (const float*)d_in[3];
    const float* W2 = (const float*)d_in[4];
    const float* b2 = (const float*)d_in[5];
    float* out = (float*)d_out;

    int N = in_sizes[0] / 128;   // 100000
    int E = in_sizes[1] / 2;     // 1600000
    const int* row = ei;
    const int* col = ei + E;

    char* ws = (char*)d_ws;
    size_t off = 0;
    auto alloc = [&](size_t bytes) -> char* {
        char* p = ws + off;
        off = WS_ALIGN(off + bytes);
        return p;
    };
    int*   bcur   = (int*)alloc(512 + (size_t)NSB * 64);   // bcur (8x16) + bcur2 (1024x16)
    int*   bcur2  = bcur + 128;
    float* dinv   = (float*)alloc((size_t)N * 4);
    unsigned int* pairs1 = (unsigned int*)alloc((size_t)NB1 * CAP1 * 4);   // 8.4MB
    unsigned int* pairs2 = (unsigned int*)alloc((size_t)NSB * CAP2 * 4);   // 12.6MB
    __half* h1s   = (__half*)alloc((size_t)N * 64 * 2);    // 12.8MB fp16
    float* h2s    = (float*)alloc((size_t)N * 2 * 4);

    int npg = (N + 7) / 8;                                  // 12500
    unsigned int magic = (unsigned int)(((1ULL << 44) + (unsigned long long)npg - 1)
                                        / (unsigned long long)npg);
    unsigned int magic2 = (unsigned int)(((1u << 20) + SPG - 1) / SPG);  // /98, exact for lc<12544

    int ntiles = (N + 15) / 16;                             // 6250
    int gblocks = (ntiles + 7) / 8;                         // 2 tiles/wave
    int nzero = 128 + NSB * 16;                             // bcur + bcur2 ints

    hipLaunchKernelGGL(k_zero, dim3((nzero + 255) / 256), dim3(256), 0, stream, bcur, nzero);
    hipLaunchKernelGGL(k_bucket, dim3((E + 2047) / 2048), dim3(256), 0, stream,
                       row, col, bcur, pairs1, E, magic, npg);
    hipLaunchKernelGGL(k_refine, dim3(512), dim3(256), 0, stream,
                       pairs1, bcur, bcur2, pairs2, magic2);
    hipLaunchKernelGGL(k_degdinv, dim3(NSB), dim3(256), 0, stream, pairs2, bcur2, dinv, npg);
    hipLaunchKernelGGL(k_gemm1, dim3(gblocks), dim3(256), 0, stream, x, W1, dinv, h1s, N);
    hipLaunchKernelGGL(k_agg1s, dim3(NSB), dim3(512), 0, stream,
                       h1s, dinv, pairs2, bcur2, b1, W2, h2s, npg);
    hipLaunchKernelGGL(k_agg2f, dim3(NSB), dim3(256), 0, stream,
                       h2s, dinv, pairs2, bcur2, b2, out, npg);
}